// Round 7
// baseline (148.332 us; speedup 1.0000x reference)
//
#include <hip/hip_runtime.h>
#include <hip/hip_bf16.h>

// Problem constants (fixed by setup_inputs)
#define NB   8      // batch
#define DK   256    // dk (4 mixtures x 64)
#define LL   2048   // Lq == Lk
#define DV   256    // dv
#define NMIX 4
#define EP2  132    // E pitch in shorts (264B rows; write banks fully spread)

typedef __attribute__((ext_vector_type(8))) short bf16x8;
typedef __attribute__((ext_vector_type(4))) float f32x4;

__device__ __forceinline__ unsigned short f2bf(float x) {
    unsigned int u = __float_as_uint(x);
    return (unsigned short)((u + 0x7FFFu + ((u >> 16) & 1u)) >> 16);  // RNE
}
__device__ __forceinline__ float bf2f(unsigned short u) {
    return __uint_as_float(((unsigned int)u) << 16);
}
__device__ __forceinline__ void nt_store4(float* p, f32x4 v) {
    __builtin_nontemporal_store(v, reinterpret_cast<f32x4*>(p));
}

// ---------------------------------------------------------------------------
// Pack K and V into exact MFMA fragment order (contiguous 1KB per wave-frag).
// Kp[((b*128+kt16)*8+cc)*64 + lane][i] = bf16(K[b][cc*32+lg*8+i][kt16*16+lc])
// Vp[((b*64+kt32)*16+vj)*64 + lane][i] = bf16(V[b][vj*16+lc][kt32*32+lg*8+i])
__global__ void pack_kv(const float* __restrict__ key,
                        const float* __restrict__ value,
                        unsigned short* __restrict__ Kp,
                        unsigned short* __restrict__ Vp) {
    const int gid0 = blockIdx.x * 256 + threadIdx.x;
    if (blockIdx.x < 2048) {
        const int gid = gid0;                 // 0 .. 524287
        const int lane = gid & 63;
        const int cc   = (gid >> 6) & 7;      // 32-ch chunk
        const int kt   = (gid >> 9) & 127;    // 16-k tile
        const int b    = gid >> 16;
        const int lg = lane >> 4, lc = lane & 15;
        const float* src = key + ((size_t)b * DK + cc * 32 + lg * 8) * LL + kt * 16 + lc;
        bf16x8 o;
        #pragma unroll
        for (int i = 0; i < 8; ++i) o[i] = (short)f2bf(src[(size_t)i * LL]);
        *reinterpret_cast<bf16x8*>(Kp + (size_t)gid * 8) = o;
    } else {
        const int gid = gid0 - 2048 * 256;    // 0 .. 524287
        const int lane = gid & 63;
        const int vj   = (gid >> 6) & 15;
        const int kt   = (gid >> 10) & 63;    // 32-k tile
        const int b    = gid >> 16;
        const int lg = lane >> 4, lc = lane & 15;
        const float* src = value + ((size_t)b * DV + vj * 16 + lc) * LL + kt * 32 + lg * 8;
        float4 v0 = *reinterpret_cast<const float4*>(src);
        float4 v1 = *reinterpret_cast<const float4*>(src + 4);
        bf16x8 o;
        o[0] = (short)f2bf(v0.x); o[1] = (short)f2bf(v0.y);
        o[2] = (short)f2bf(v0.z); o[3] = (short)f2bf(v0.w);
        o[4] = (short)f2bf(v1.x); o[5] = (short)f2bf(v1.y);
        o[6] = (short)f2bf(v1.z); o[7] = (short)f2bf(v1.w);
        *reinterpret_cast<bf16x8*>(Vp + (size_t)gid * 8) = o;
    }
}

// avg_query: one block per (b*DK + d) row, mean over LL
__global__ void avg_k(const float* __restrict__ q, float* __restrict__ avg) {
    const int row = blockIdx.x;
    const float* p = q + (size_t)row * LL;
    float s = 0.f;
    for (int i = threadIdx.x; i < LL; i += 256) s += p[i];
    #pragma unroll
    for (int off = 32; off >= 1; off >>= 1) s += __shfl_down(s, off);
    __shared__ float ps[4];
    if ((threadIdx.x & 63) == 0) ps[threadIdx.x >> 6] = s;
    __syncthreads();
    if (threadIdx.x == 0)
        avg[row] = (ps[0] + ps[1] + ps[2] + ps[3]) * (1.0f / LL);
}

// pi = softmax_m( w[m,:] . avg[b,:] ) ; one wave per b
__global__ void pi_k(const float* __restrict__ wgt, const float* __restrict__ avg,
                     float* __restrict__ piOut) {
    const int b = blockIdx.x;
    const int l = threadIdx.x;   // 0..63
    float part[NMIX] = {0.f, 0.f, 0.f, 0.f};
    for (int d = l; d < DK; d += 64) {
        float a = avg[b * DK + d];
        #pragma unroll
        for (int m = 0; m < NMIX; ++m) part[m] += wgt[m * DK + d] * a;
    }
    #pragma unroll
    for (int off = 1; off < 64; off <<= 1) {
        #pragma unroll
        for (int m = 0; m < NMIX; ++m) part[m] += __shfl_xor(part[m], off);
    }
    float mx = fmaxf(fmaxf(part[0], part[1]), fmaxf(part[2], part[3]));
    float e0 = __expf(part[0] - mx), e1 = __expf(part[1] - mx);
    float e2 = __expf(part[2] - mx), e3 = __expf(part[3] - mx);
    float z = e0 + e1 + e2 + e3;
    float mine = (l == 0) ? e0 : (l == 1) ? e1 : (l == 2) ? e2 : e3;
    if (l < NMIX) piOut[b * NMIX + l] = mine / z;
}

// ---------------------------------------------------------------------------
// Main kernel v7: fused Z + attn + O.
// grid 512 = b(8, bid>>6) x qt(64, bid&63) -> XCD = qt%8 (write-spread).
// 512 threads / 8 waves, 32 q-rows per block, 2 blocks/CU (overlapping
// barrier groups). Wave w = (wq = w>>2 in 0..1 : 16 q-rows, wk = w&3).
// Phase 1 (barrier-free): Z-sweep — wave (wq,wk) sums exp over its k-quarter;
//   one LDS reduce -> C[m][r] = log2(pi_m/Z_q).
// Phase 2, per 128-k window j (16 iters, ONE barrier each):
//   QK: wave computes 16q x 32k from contiguous Kp frags, E -> dbuf LDS tile.
//   barrier. attn tile store (nontemporal f32x4). PV: wave owns vj {2w,2w+1},
//   Vp frags read exactly once per block.
__launch_bounds__(512, 4)
__global__ void mos_attn(const float* __restrict__ query,
                         const unsigned short* __restrict__ Kp,
                         const unsigned short* __restrict__ Vp,
                         const float* __restrict__ piAll,
                         float* __restrict__ out,
                         float* __restrict__ attn) {
    const int bid = blockIdx.x;
    const int b   = bid >> 6;            // batch
    const int qt  = bid & 63;            // XCD = qt % 8 -> writes spread
    const int qb  = qt * 32;
    const int tid = threadIdx.x;
    const int w = tid >> 6, lane = tid & 63, lg = lane >> 4, lc = lane & 15;
    const int wq = w >> 2, wk = w & 3;

    __shared__ __align__(16) unsigned short E[2][32 * EP2];   // 16.9 KB
    __shared__ float Zp[2][4][4][4][4];                       // [wq][wk][m][lg][r]

    // Q fragments for this wave's 16 q-rows (A[row=q=lc][ch=lg*8+i])
    bf16x8 qf[4][2];
    #pragma unroll
    for (int m = 0; m < 4; ++m)
        #pragma unroll
        for (int c = 0; c < 2; ++c) {
            const float* src = query + ((size_t)b * DK + m * 64 + c * 32 + lg * 8) * LL
                               + qb + wq * 16 + lc;
            bf16x8 f;
            #pragma unroll
            for (int i = 0; i < 8; ++i) f[i] = (short)f2bf(src[(size_t)i * LL]);
            qf[m][c] = f;
        }

    const unsigned short* kpB = Kp + (size_t)b * 128 * 8 * 512;
    const unsigned short* vpB = Vp + (size_t)b * 64 * 16 * 512;
    const float ES = 0.09016844005555896f;   // log2(e)/16

    // ---- Phase 1: Z-sweep over this wave's k-quarter (32 ktiles) ----
    {
        float zs[4][4];
        #pragma unroll
        for (int m = 0; m < 4; ++m)
            #pragma unroll
            for (int r = 0; r < 4; ++r) zs[m][r] = 0.f;
        for (int t = 0; t < 32; ++t) {
            const unsigned short* kp = kpB + (size_t)(wk * 32 + t) * 8 * 512 + lane * 8;
            #pragma unroll
            for (int m = 0; m < 4; ++m) {
                bf16x8 k0 = *reinterpret_cast<const bf16x8*>(kp + (m * 2 + 0) * 512);
                bf16x8 k1 = *reinterpret_cast<const bf16x8*>(kp + (m * 2 + 1) * 512);
                f32x4 s = {0.f, 0.f, 0.f, 0.f};
                s = __builtin_amdgcn_mfma_f32_16x16x32_bf16(qf[m][0], k0, s, 0, 0, 0);
                s = __builtin_amdgcn_mfma_f32_16x16x32_bf16(qf[m][1], k1, s, 0, 0, 0);
                #pragma unroll
                for (int r = 0; r < 4; ++r)
                    zs[m][r] += __builtin_amdgcn_exp2f(s[r] * ES);
            }
        }
        #pragma unroll
        for (int m = 0; m < 4; ++m)
            #pragma unroll
            for (int r = 0; r < 4; ++r) {
                float v = zs[m][r];
                v += __shfl_xor(v, 1);
                v += __shfl_xor(v, 2);
                v += __shfl_xor(v, 4);
                v += __shfl_xor(v, 8);
                zs[m][r] = v;
            }
        if (lc == 0) {
            #pragma unroll
            for (int m = 0; m < 4; ++m)
                #pragma unroll
                for (int r = 0; r < 4; ++r) Zp[wq][wk][m][lg][r] = zs[m][r];
        }
    }
    __syncthreads();

    // C[m][r] = log2(pi_m / Z) for q = qb + wq*16 + lg*4 + r
    float C[4][4];
    #pragma unroll
    for (int m = 0; m < 4; ++m) {
        const float pim = piAll[b * NMIX + m];
        #pragma unroll
        for (int r = 0; r < 4; ++r) {
            float z = Zp[wq][0][m][lg][r] + Zp[wq][1][m][lg][r]
                    + Zp[wq][2][m][lg][r] + Zp[wq][3][m][lg][r];
            C[m][r] = __log2f(pim / z);
        }
    }

    f32x4 oacc[2][2];   // [qg][vjj]
    #pragma unroll
    for (int qg = 0; qg < 2; ++qg)
        #pragma unroll
        for (int vv = 0; vv < 2; ++vv) oacc[qg][vv] = (f32x4){0.f, 0.f, 0.f, 0.f};

    // attn streaming pointer (row = tid>>4 in 0..31, col base = (tid&15)*8)
    float* arow = attn + ((size_t)b * LL + qb + (tid >> 4)) * LL + (tid & 15) * 8;

    // ---- Phase 2: 16 windows of 128 k ----
    for (int j = 0; j < 16; ++j) {
        const int buf = j & 1;
        #pragma unroll
        for (int kt = 0; kt < 2; ++kt) {
            const int ktile = j * 8 + wk * 2 + kt;
            const unsigned short* kp = kpB + (size_t)ktile * 8 * 512 + lane * 8;
            float av[4] = {0.f, 0.f, 0.f, 0.f};
            #pragma unroll
            for (int m = 0; m < 4; ++m) {
                bf16x8 k0 = *reinterpret_cast<const bf16x8*>(kp + (m * 2 + 0) * 512);
                bf16x8 k1 = *reinterpret_cast<const bf16x8*>(kp + (m * 2 + 1) * 512);
                f32x4 s = {0.f, 0.f, 0.f, 0.f};
                s = __builtin_amdgcn_mfma_f32_16x16x32_bf16(qf[m][0], k0, s, 0, 0, 0);
                s = __builtin_amdgcn_mfma_f32_16x16x32_bf16(qf[m][1], k1, s, 0, 0, 0);
                #pragma unroll
                for (int r = 0; r < 4; ++r)
                    av[r] += __builtin_amdgcn_exp2f(fmaf(s[r], ES, C[m][r]));
            }
            #pragma unroll
            for (int r = 0; r < 4; ++r)
                E[buf][(wq * 16 + lg * 4 + r) * EP2 + wk * 32 + kt * 16 + lc] =
                    f2bf(av[r]);
        }
        __syncthreads();

        // ---- attn store: nontemporal, coalesced f32x4 ----
        {
            bf16x8 e = *reinterpret_cast<const bf16x8*>(
                &E[buf][(tid >> 4) * EP2 + (tid & 15) * 8]);
            f32x4 f0, f1;
            #pragma unroll
            for (int i = 0; i < 4; ++i) {
                f0[i] = bf2f((unsigned short)e[i]);
                f1[i] = bf2f((unsigned short)e[i + 4]);
            }
            nt_store4(arow + j * 128, f0);
            nt_store4(arow + j * 128 + 4, f1);
        }

        // ---- PV: wave owns vj = {2w, 2w+1}; k = full 128 window ----
        #pragma unroll
        for (int kc = 0; kc < 4; ++kc) {
            bf16x8 ea0 = *reinterpret_cast<const bf16x8*>(
                &E[buf][lc * EP2 + kc * 32 + lg * 8]);
            bf16x8 ea1 = *reinterpret_cast<const bf16x8*>(
                &E[buf][(16 + lc) * EP2 + kc * 32 + lg * 8]);
            const unsigned short* vpt =
                vpB + ((size_t)(j * 4 + kc) * 16 + w * 2) * 512 + lane * 8;
            bf16x8 vf0 = *reinterpret_cast<const bf16x8*>(vpt);
            bf16x8 vf1 = *reinterpret_cast<const bf16x8*>(vpt + 512);
            oacc[0][0] = __builtin_amdgcn_mfma_f32_16x16x32_bf16(ea0, vf0, oacc[0][0], 0, 0, 0);
            oacc[1][0] = __builtin_amdgcn_mfma_f32_16x16x32_bf16(ea1, vf0, oacc[1][0], 0, 0, 0);
            oacc[0][1] = __builtin_amdgcn_mfma_f32_16x16x32_bf16(ea0, vf1, oacc[0][1], 0, 0, 0);
            oacc[1][1] = __builtin_amdgcn_mfma_f32_16x16x32_bf16(ea1, vf1, oacc[1][1], 0, 0, 0);
        }
        // single barrier per j: next QK writes E[buf^1]; E[buf] is only
        // rewritten after the NEXT barrier, so PV/attn reads stay safe.
    }

    // out: q = qb + qg*16 + lg*4 + d ; vcol = (w*2+vjj)*16 + lc
    #pragma unroll
    for (int qg = 0; qg < 2; ++qg)
        #pragma unroll
        for (int vv = 0; vv < 2; ++vv)
            #pragma unroll
            for (int d = 0; d < 4; ++d)
                out[((size_t)b * LL + qb + qg * 16 + lg * 4 + d) * DV
                    + (w * 2 + vv) * 16 + lc] = oacc[qg][vv][d];
}

// ---------------------------------------------------------------------------
extern "C" void kernel_launch(void* const* d_in, const int* in_sizes, int n_in,
                              void* d_out, int out_size, void* d_ws, size_t ws_size,
                              hipStream_t stream) {
    const float* query   = (const float*)d_in[0];   // (8, 256, 2048)
    const float* key     = (const float*)d_in[1];   // (8, 256, 2048)
    const float* value   = (const float*)d_in[2];   // (8, 256, 2048)
    const float* weights = (const float*)d_in[3];   // (4, 256)

    float* out  = (float*)d_out;                    // (8, 2048, 256)
    float* attn = out + (size_t)NB * LL * DV;       // (8, 2048, 2048)

    // workspace (~16.8 MB)
    char* ws = (char*)d_ws;
    float* avg = (float*)ws;                              // 8KB
    float* pi  = (float*)(ws + 8192);                     // 32B
    unsigned short* Kp = (unsigned short*)(ws + 16384);   // 8.4MB packed K frags
    unsigned short* Vp = Kp + (size_t)NB * LL * DK;       // 8.4MB packed V frags

    avg_k<<<NB * DK, 256, 0, stream>>>(query, avg);
    pi_k<<<NB, 64, 0, stream>>>(weights, avg, pi);
    pack_kv<<<4096, 256, 0, stream>>>(key, value, Kp, Vp);
    mos_attn<<<512, 512, 0, stream>>>(query, Kp, Vp, pi, out, attn);
}

// Round 8
// 128.503 us; speedup vs baseline: 1.1543x; 1.1543x over previous
//
#include <hip/hip_runtime.h>
#include <hip/hip_bf16.h>

// Problem constants (fixed by setup_inputs)
#define NB   8      // batch
#define DK   256    // dk (4 mixtures x 64)
#define LL   2048   // Lq == Lk
#define DV   256    // dv
#define NMIX 4
#define EP   72     // E pitch (shorts): 144B rows -> 16B-aligned bf16x8 reads

typedef __attribute__((ext_vector_type(8))) short bf16x8;
typedef __attribute__((ext_vector_type(4))) short bf16x4;
typedef __attribute__((ext_vector_type(4))) float f32x4;

__device__ __forceinline__ unsigned short f2bf(float x) {
    unsigned int u = __float_as_uint(x);
    return (unsigned short)((u + 0x7FFFu + ((u >> 16) & 1u)) >> 16);  // RNE
}
__device__ __forceinline__ float bf2f(unsigned short u) {
    return __uint_as_float(((unsigned int)u) << 16);
}
__device__ __forceinline__ void nt_store4(float* p, f32x4 v) {
    __builtin_nontemporal_store(v, reinterpret_cast<f32x4*>(p));
}
// async global->LDS: per-lane global src; LDS dest = uniform base + lane*16B
__device__ __forceinline__ void gl16(const unsigned short* g, unsigned short* l) {
    __builtin_amdgcn_global_load_lds(
        (const __attribute__((address_space(1))) unsigned int*)(const void*)g,
        (__attribute__((address_space(3))) unsigned int*)(void*)l, 16, 0, 0);
}

// ---------------------------------------------------------------------------
// Pack K and V into exact MFMA fragment order (contiguous 1KB per wave-frag).
// Kp[((b*128+kt16)*8+cc)*512 + lane*8+i] = bf16(K[b][cc*32+lg*8+i][kt16*16+lc])
// Vp[((b*64+kt32)*16+vj)*512 + lane*8+i] = bf16(V[b][vj*16+lc][kt32*32+lg*8+i])
__global__ void pack_kv(const float* __restrict__ key,
                        const float* __restrict__ value,
                        unsigned short* __restrict__ Kp,
                        unsigned short* __restrict__ Vp) {
    const int gid0 = blockIdx.x * 256 + threadIdx.x;
    if (blockIdx.x < 2048) {
        const int gid = gid0;                 // 0 .. 524287
        const int lane = gid & 63;
        const int cc   = (gid >> 6) & 7;      // 32-ch chunk
        const int kt   = (gid >> 9) & 127;    // 16-k tile
        const int b    = gid >> 16;
        const int lg = lane >> 4, lc = lane & 15;
        const float* src = key + ((size_t)b * DK + cc * 32 + lg * 8) * LL + kt * 16 + lc;
        bf16x8 o;
        #pragma unroll
        for (int i = 0; i < 8; ++i) o[i] = (short)f2bf(src[(size_t)i * LL]);
        *reinterpret_cast<bf16x8*>(Kp + (size_t)gid * 8) = o;
    } else {
        const int gid = gid0 - 2048 * 256;    // 0 .. 524287
        const int lane = gid & 63;
        const int vj   = (gid >> 6) & 15;
        const int kt   = (gid >> 10) & 63;    // 32-k tile
        const int b    = gid >> 16;
        const int lg = lane >> 4, lc = lane & 15;
        const float* src = value + ((size_t)b * DV + vj * 16 + lc) * LL + kt * 32 + lg * 8;
        float4 v0 = *reinterpret_cast<const float4*>(src);
        float4 v1 = *reinterpret_cast<const float4*>(src + 4);
        bf16x8 o;
        o[0] = (short)f2bf(v0.x); o[1] = (short)f2bf(v0.y);
        o[2] = (short)f2bf(v0.z); o[3] = (short)f2bf(v0.w);
        o[4] = (short)f2bf(v1.x); o[5] = (short)f2bf(v1.y);
        o[6] = (short)f2bf(v1.z); o[7] = (short)f2bf(v1.w);
        *reinterpret_cast<bf16x8*>(Vp + (size_t)gid * 8) = o;
    }
}

// avg_query: one block per (b*DK + d) row, mean over LL
__global__ void avg_k(const float* __restrict__ q, float* __restrict__ avg) {
    const int row = blockIdx.x;
    const float* p = q + (size_t)row * LL;
    float s = 0.f;
    for (int i = threadIdx.x; i < LL; i += 256) s += p[i];
    #pragma unroll
    for (int off = 32; off >= 1; off >>= 1) s += __shfl_down(s, off);
    __shared__ float ps[4];
    if ((threadIdx.x & 63) == 0) ps[threadIdx.x >> 6] = s;
    __syncthreads();
    if (threadIdx.x == 0)
        avg[row] = (ps[0] + ps[1] + ps[2] + ps[3]) * (1.0f / LL);
}

// pi = softmax_m( w[m,:] . avg[b,:] ) ; one wave per b
__global__ void pi_k(const float* __restrict__ wgt, const float* __restrict__ avg,
                     float* __restrict__ piOut) {
    const int b = blockIdx.x;
    const int l = threadIdx.x;   // 0..63
    float part[NMIX] = {0.f, 0.f, 0.f, 0.f};
    for (int d = l; d < DK; d += 64) {
        float a = avg[b * DK + d];
        #pragma unroll
        for (int m = 0; m < NMIX; ++m) part[m] += wgt[m * DK + d] * a;
    }
    #pragma unroll
    for (int off = 1; off < 64; off <<= 1) {
        #pragma unroll
        for (int m = 0; m < NMIX; ++m) part[m] += __shfl_xor(part[m], off);
    }
    float mx = fmaxf(fmaxf(part[0], part[1]), fmaxf(part[2], part[3]));
    float e0 = __expf(part[0] - mx), e1 = __expf(part[1] - mx);
    float e2 = __expf(part[2] - mx), e3 = __expf(part[3] - mx);
    float z = e0 + e1 + e2 + e3;
    float mine = (l == 0) ? e0 : (l == 1) ? e1 : (l == 2) ? e2 : e3;
    if (l < NMIX) piOut[b * NMIX + l] = mine / z;
}

// ---------------------------------------------------------------------------
// Q A-fragment hoist from raw f32 query: A[row=q=lc][ch=lg*8+i]; qf[qt][m][c].
__device__ __forceinline__ void hoist_q2(const float* __restrict__ query,
                                         int b, int qrow0, int lg, int lc,
                                         bf16x8 qf[2][4][2]) {
    #pragma unroll
    for (int qt = 0; qt < 2; ++qt)
        #pragma unroll
        for (int m = 0; m < 4; ++m)
            #pragma unroll
            for (int c = 0; c < 2; ++c) {
                const float* src = query + ((size_t)b * DK + m * 64 + c * 32 + lg * 8) * LL
                                   + qrow0 + qt * 16 + lc;
                bf16x8 f;
                #pragma unroll
                for (int i = 0; i < 8; ++i) f[i] = (short)f2bf(src[(size_t)i * LL]);
                qf[qt][m][c] = f;
            }
}

// ---------------------------------------------------------------------------
// Z pre-pass (unchanged from R6, known-good):
// Zh[kh][b][q][m] = sum_{k in half} exp2(S*ES)
// grid 1024 = b(8) x qt64(64, 32 q-rows) x kh(2). 4 waves k-split the half.
__launch_bounds__(256, 4)
__global__ void zsum_k(const float* __restrict__ query,
                       const unsigned short* __restrict__ Kp,
                       float* __restrict__ Zh) {
    const int bid = blockIdx.x;
    const int b    = bid & 7;             // XCD affinity
    const int qt64 = (bid >> 3) & 63;
    const int kh   = bid >> 9;
    const int qb   = qt64 * 32;
    const int tid  = threadIdx.x;
    const int w = tid >> 6, lane = tid & 63, lg = lane >> 4, lc = lane & 15;

    bf16x8 qf[2][4][2];
    hoist_q2(query, b, qb, lg, lc, qf);

    const unsigned short* kpB = Kp + (size_t)b * 128 * 8 * 512;
    const float ES = 0.09016844005555896f;   // log2(e)/16

    float zs[2][4][4];
    #pragma unroll
    for (int qt = 0; qt < 2; ++qt)
        #pragma unroll
        for (int m = 0; m < 4; ++m)
            #pragma unroll
            for (int r = 0; r < 4; ++r) zs[qt][m][r] = 0.f;

    for (int t = 0; t < 16; ++t) {
        const int ktile = kh * 64 + w * 16 + t;
        const unsigned short* kp = kpB + (size_t)ktile * 8 * 512 + lane * 8;
        #pragma unroll
        for (int m = 0; m < 4; ++m) {
            bf16x8 k0 = *reinterpret_cast<const bf16x8*>(kp + (m * 2 + 0) * 512);
            bf16x8 k1 = *reinterpret_cast<const bf16x8*>(kp + (m * 2 + 1) * 512);
            #pragma unroll
            for (int qt = 0; qt < 2; ++qt) {
                f32x4 s = {0.f, 0.f, 0.f, 0.f};
                s = __builtin_amdgcn_mfma_f32_16x16x32_bf16(qf[qt][m][0], k0, s, 0, 0, 0);
                s = __builtin_amdgcn_mfma_f32_16x16x32_bf16(qf[qt][m][1], k1, s, 0, 0, 0);
                #pragma unroll
                for (int r = 0; r < 4; ++r)
                    zs[qt][m][r] += __builtin_amdgcn_exp2f(s[r] * ES);
            }
        }
    }
    #pragma unroll
    for (int qt = 0; qt < 2; ++qt)
        #pragma unroll
        for (int m = 0; m < 4; ++m)
            #pragma unroll
            for (int r = 0; r < 4; ++r) {
                float v = zs[qt][m][r];
                v += __shfl_xor(v, 1);
                v += __shfl_xor(v, 2);
                v += __shfl_xor(v, 4);
                v += __shfl_xor(v, 8);
                zs[qt][m][r] = v;
            }
    __shared__ float Zp[4][2][4][4][4];   // [w][qt][lg][m][r]
    if (lc == 0) {
        #pragma unroll
        for (int qt = 0; qt < 2; ++qt)
            #pragma unroll
            for (int m = 0; m < 4; ++m)
                #pragma unroll
                for (int r = 0; r < 4; ++r) Zp[w][qt][lg][m][r] = zs[qt][m][r];
    }
    __syncthreads();
    if (tid < 128) {
        const int q = tid >> 2, m = tid & 3;
        const int qt = q >> 4, g = (q >> 2) & 3, r = q & 3;
        float z = Zp[0][qt][g][m][r] + Zp[1][qt][g][m][r]
                + Zp[2][qt][g][m][r] + Zp[3][qt][g][m][r];
        Zh[(((size_t)kh * NB + b) * LL + qb + q) * NMIX + m] = z;
    }
}

// ---------------------------------------------------------------------------
// Main kernel v8: read-once LDS staging for K AND V.
// grid 256 = b(8, bid&7 -> XCD-local L2) x qt(32, 64 q-rows); 1024 thr / 16 w.
// Window = 64 k. Per window (2 barriers):
//   issue gl16 stage of window j+1 (linear 32KB+32KB frag memcpy, dbuf)
//   QK: wave (wq=w>>2, wk=w&3) does 16q x 16k from LDS K-frags -> E[j&1] LDS
//   __syncthreads (drains the early-issued gl16s under QK's shadow)
//   attn store (nontemporal f32x4 from E) + PV: wave w owns vj=w, E as A-frags
//   __syncthreads (Ks/Vs[j&1] free for stage j+2)
__launch_bounds__(1024, 4)
__global__ void mos_attn(const float* __restrict__ query,
                         const unsigned short* __restrict__ Kp,
                         const unsigned short* __restrict__ Vp,
                         const float* __restrict__ Zh,
                         const float* __restrict__ piAll,
                         float* __restrict__ out,
                         float* __restrict__ attn) {
    const int bid = blockIdx.x;
    const int b   = bid & 7;             // XCD affinity: all of b on one XCD
    const int qt  = bid >> 3;            // 0..31
    const int qb  = qt * 64;
    const int tid = threadIdx.x;
    const int w = tid >> 6, lane = tid & 63, lg = lane >> 4, lc = lane & 15;
    const int wq = w >> 2, wk = w & 3;

    __shared__ __align__(16) unsigned short Ks[2][16384];   // 2 x 32KB (32 frags)
    __shared__ __align__(16) unsigned short Vs[2][16384];   // 2 x 32KB (32 frags)
    __shared__ __align__(16) unsigned short E[2][64 * EP];  // 2 x 9.2KB

    // Q A-fragments for this wave's 16 q-rows: A[row=q=lc][ch]
    bf16x8 qf[4][2];
    #pragma unroll
    for (int m = 0; m < 4; ++m)
        #pragma unroll
        for (int c = 0; c < 2; ++c) {
            const float* src = query + ((size_t)b * DK + m * 64 + c * 32 + lg * 8) * LL
                               + qb + wq * 16 + lc;
            bf16x8 f;
            #pragma unroll
            for (int i = 0; i < 8; ++i) f[i] = (short)f2bf(src[(size_t)i * LL]);
            qf[m][c] = f;
        }

    // C[m][r] = log2(pi_m / Z) for q = qb + wq*16 + lg*4 + r
    float C[4][4];
    #pragma unroll
    for (int r = 0; r < 4; ++r) {
        const int q = qb + wq * 16 + lg * 4 + r;
        #pragma unroll
        for (int m = 0; m < 4; ++m) {
            float z = Zh[((size_t)b * LL + q) * NMIX + m]
                    + Zh[((size_t)(NB + b) * LL + q) * NMIX + m];
            C[m][r] = __log2f(piAll[b * NMIX + m] / z);
        }
    }

    // window j occupies frags [j*32 .. j*32+31] in both Kp and Vp (contiguous)
    const unsigned short* kpB = Kp + (size_t)b * 128 * 8 * 512;
    const unsigned short* vpB = Vp + (size_t)b * 64 * 16 * 512;
    const int sOff0 = (w * 2 + 0) * 512;      // this wave's two 1KB stage slots
    const int sOff1 = (w * 2 + 1) * 512;
    const float ES = 0.09016844005555896f;    // log2(e)/16

    f32x4 oacc[4];
    #pragma unroll
    for (int qg = 0; qg < 4; ++qg) oacc[qg] = (f32x4){0.f, 0.f, 0.f, 0.f};

    // attn streaming pointer: row = tid>>4 (0..63), col = (tid&15)*4
    float* arow = attn + ((size_t)b * LL + qb + (tid >> 4)) * LL + (tid & 15) * 4;

    // prologue: stage window 0 into buf 0
    gl16(kpB + 0 * 16384 + sOff0 + lane * 8, &Ks[0][sOff0]);
    gl16(kpB + 0 * 16384 + sOff1 + lane * 8, &Ks[0][sOff1]);
    gl16(vpB + 0 * 16384 + sOff0 + lane * 8, &Vs[0][sOff0]);
    gl16(vpB + 0 * 16384 + sOff1 + lane * 8, &Vs[0][sOff1]);
    __syncthreads();

    for (int j = 0; j < 32; ++j) {
        const int buf = j & 1;
        if (j < 31) {   // issue next-window stage early; drained by bar#1
            const size_t src = (size_t)(j + 1) * 16384;
            gl16(kpB + src + sOff0 + lane * 8, &Ks[buf ^ 1][sOff0]);
            gl16(kpB + src + sOff1 + lane * 8, &Ks[buf ^ 1][sOff1]);
            gl16(vpB + src + sOff0 + lane * 8, &Vs[buf ^ 1][sOff0]);
            gl16(vpB + src + sOff1 + lane * 8, &Vs[buf ^ 1][sOff1]);
        }

        // ---- QK: wave (wq,wk) -> 16q x 16k from LDS K frags ----
        {
            const unsigned short* kf = &Ks[buf][(wk * 8) * 512 + lane * 8];
            float av[4] = {0.f, 0.f, 0.f, 0.f};
            #pragma unroll
            for (int m = 0; m < 4; ++m) {
                bf16x8 k0 = *reinterpret_cast<const bf16x8*>(kf + (m * 2 + 0) * 512);
                bf16x8 k1 = *reinterpret_cast<const bf16x8*>(kf + (m * 2 + 1) * 512);
                f32x4 s = {0.f, 0.f, 0.f, 0.f};
                s = __builtin_amdgcn_mfma_f32_16x16x32_bf16(qf[m][0], k0, s, 0, 0, 0);
                s = __builtin_amdgcn_mfma_f32_16x16x32_bf16(qf[m][1], k1, s, 0, 0, 0);
                #pragma unroll
                for (int r = 0; r < 4; ++r)
                    av[r] += __builtin_amdgcn_exp2f(fmaf(s[r], ES, C[m][r]));
            }
            #pragma unroll
            for (int r = 0; r < 4; ++r)
                E[buf][(wq * 16 + lg * 4 + r) * EP + wk * 16 + lc] = f2bf(av[r]);
        }
        __syncthreads();   // bar#1: E ready; stage(j+1) drained (vmcnt 0)

        // ---- attn store: 64q x 64k tile, coalesced nontemporal f32x4 ----
        {
            bf16x4 e = *reinterpret_cast<const bf16x4*>(
                &E[buf][(tid >> 4) * EP + (tid & 15) * 4]);
            f32x4 f;
            #pragma unroll
            for (int i = 0; i < 4; ++i) f[i] = bf2f((unsigned short)e[i]);
            nt_store4(arow + j * 64, f);
        }

        // ---- PV: wave owns vj = w; 2 k-chunks of 32 ----
        #pragma unroll
        for (int kc = 0; kc < 2; ++kc) {
            bf16x8 vf = *reinterpret_cast<const bf16x8*>(
                &Vs[buf][(kc * 16 + w) * 512 + lane * 8]);
            #pragma unroll
            for (int qg = 0; qg < 4; ++qg) {
                bf16x8 ea = *reinterpret_cast<const bf16x8*>(
                    &E[buf][(qg * 16 + lc) * EP + kc * 32 + lg * 8]);
                oacc[qg] = __builtin_amdgcn_mfma_f32_16x16x32_bf16(ea, vf, oacc[qg], 0, 0, 0);
            }
        }
        __syncthreads();   // bar#2: Ks/Vs[buf] free for stage(j+2)
    }

    // out: q = qb + qg*16 + lg*4 + r ; v = w*16 + lc
    #pragma unroll
    for (int qg = 0; qg < 4; ++qg)
        #pragma unroll
        for (int r = 0; r < 4; ++r)
            out[((size_t)b * LL + qb + qg * 16 + lg * 4 + r) * DV + w * 16 + lc] =
                oacc[qg][r];
}

// ---------------------------------------------------------------------------
extern "C" void kernel_launch(void* const* d_in, const int* in_sizes, int n_in,
                              void* d_out, int out_size, void* d_ws, size_t ws_size,
                              hipStream_t stream) {
    const float* query   = (const float*)d_in[0];   // (8, 256, 2048)
    const float* key     = (const float*)d_in[1];   // (8, 256, 2048)
    const float* value   = (const float*)d_in[2];   // (8, 256, 2048)
    const float* weights = (const float*)d_in[3];   // (4, 256)

    float* out  = (float*)d_out;                    // (8, 2048, 256)
    float* attn = out + (size_t)NB * LL * DV;       // (8, 2048, 2048)

    // workspace (~17.3 MB)
    char* ws = (char*)d_ws;
    float* avg = (float*)ws;                              // 8KB
    float* pi  = (float*)(ws + 8192);                     // 32B
    float* Zh  = (float*)(ws + 12288);                    // 512KB
    unsigned short* Kp = (unsigned short*)(ws + 536576);  // 8.4MB packed K frags
    unsigned short* Vp = Kp + (size_t)NB * LL * DK;       // 8.4MB packed V frags

    avg_k<<<NB * DK, 256, 0, stream>>>(query, avg);
    pi_k<<<NB, 64, 0, stream>>>(weights, avg, pi);
    pack_kv<<<4096, 256, 0, stream>>>(key, value, Kp, Vp);
    zsum_k<<<1024, 256, 0, stream>>>(query, Kp, Zh);
    mos_attn<<<256, 1024, 0, stream>>>(query, Kp, Vp, Zh, pi, out, attn);
}

// Round 9
// 124.071 us; speedup vs baseline: 1.1955x; 1.0357x over previous
//
#include <hip/hip_runtime.h>
#include <hip/hip_bf16.h>

// Problem constants (fixed by setup_inputs)
#define NB   8      // batch
#define DK   256    // dk (4 mixtures x 64)
#define LL   2048   // Lq == Lk
#define DV   256    // dv
#define NMIX 4
#define EP   72     // E pitch (shorts); rows 144B; swizzled cols

typedef __attribute__((ext_vector_type(8))) short bf16x8;
typedef __attribute__((ext_vector_type(4))) short bf16x4;
typedef __attribute__((ext_vector_type(4))) float f32x4;

__device__ __forceinline__ unsigned short f2bf(float x) {
    unsigned int u = __float_as_uint(x);
    return (unsigned short)((u + 0x7FFFu + ((u >> 16) & 1u)) >> 16);  // RNE
}
__device__ __forceinline__ float bf2f(unsigned short u) {
    return __uint_as_float(((unsigned int)u) << 16);
}
__device__ __forceinline__ void nt_store4(float* p, f32x4 v) {
    __builtin_nontemporal_store(v, reinterpret_cast<f32x4*>(p));
}
// async global->LDS: per-lane global src; LDS dest = uniform base + lane*16B
__device__ __forceinline__ void gl16(const unsigned short* g, unsigned short* l) {
    __builtin_amdgcn_global_load_lds(
        (const __attribute__((address_space(1))) unsigned int*)(const void*)g,
        (__attribute__((address_space(3))) unsigned int*)(void*)l, 16, 0, 0);
}

// ---------------------------------------------------------------------------
// Pack K and V into exact MFMA fragment order (contiguous 1KB per wave-frag).
// Kp[((b*128+kt16)*8+cc)*512 + lane*8+i] = bf16(K[b][cc*32+lg*8+i][kt16*16+lc])
// Vp[((b*64+kt32)*16+vj)*512 + lane*8+i] = bf16(V[b][vj*16+lc][kt32*32+lg*8+i])
__global__ void pack_kv(const float* __restrict__ key,
                        const float* __restrict__ value,
                        unsigned short* __restrict__ Kp,
                        unsigned short* __restrict__ Vp) {
    const int gid0 = blockIdx.x * 256 + threadIdx.x;
    if (blockIdx.x < 2048) {
        const int gid = gid0;                 // 0 .. 524287
        const int lane = gid & 63;
        const int cc   = (gid >> 6) & 7;      // 32-ch chunk
        const int kt   = (gid >> 9) & 127;    // 16-k tile
        const int b    = gid >> 16;
        const int lg = lane >> 4, lc = lane & 15;
        const float* src = key + ((size_t)b * DK + cc * 32 + lg * 8) * LL + kt * 16 + lc;
        bf16x8 o;
        #pragma unroll
        for (int i = 0; i < 8; ++i) o[i] = (short)f2bf(src[(size_t)i * LL]);
        *reinterpret_cast<bf16x8*>(Kp + (size_t)gid * 8) = o;
    } else {
        const int gid = gid0 - 2048 * 256;    // 0 .. 524287
        const int lane = gid & 63;
        const int vj   = (gid >> 6) & 15;
        const int kt   = (gid >> 10) & 63;    // 32-k tile
        const int b    = gid >> 16;
        const int lg = lane >> 4, lc = lane & 15;
        const float* src = value + ((size_t)b * DV + vj * 16 + lc) * LL + kt * 32 + lg * 8;
        float4 v0 = *reinterpret_cast<const float4*>(src);
        float4 v1 = *reinterpret_cast<const float4*>(src + 4);
        bf16x8 o;
        o[0] = (short)f2bf(v0.x); o[1] = (short)f2bf(v0.y);
        o[2] = (short)f2bf(v0.z); o[3] = (short)f2bf(v0.w);
        o[4] = (short)f2bf(v1.x); o[5] = (short)f2bf(v1.y);
        o[6] = (short)f2bf(v1.z); o[7] = (short)f2bf(v1.w);
        *reinterpret_cast<bf16x8*>(Vp + (size_t)gid * 8) = o;
    }
}

// avg_query: one block per (b*DK + d) row, mean over LL
__global__ void avg_k(const float* __restrict__ q, float* __restrict__ avg) {
    const int row = blockIdx.x;
    const float* p = q + (size_t)row * LL;
    float s = 0.f;
    for (int i = threadIdx.x; i < LL; i += 256) s += p[i];
    #pragma unroll
    for (int off = 32; off >= 1; off >>= 1) s += __shfl_down(s, off);
    __shared__ float ps[4];
    if ((threadIdx.x & 63) == 0) ps[threadIdx.x >> 6] = s;
    __syncthreads();
    if (threadIdx.x == 0)
        avg[row] = (ps[0] + ps[1] + ps[2] + ps[3]) * (1.0f / LL);
}

// pi = softmax_m( w[m,:] . avg[b,:] ) ; one wave per b
__global__ void pi_k(const float* __restrict__ wgt, const float* __restrict__ avg,
                     float* __restrict__ piOut) {
    const int b = blockIdx.x;
    const int l = threadIdx.x;   // 0..63
    float part[NMIX] = {0.f, 0.f, 0.f, 0.f};
    for (int d = l; d < DK; d += 64) {
        float a = avg[b * DK + d];
        #pragma unroll
        for (int m = 0; m < NMIX; ++m) part[m] += wgt[m * DK + d] * a;
    }
    #pragma unroll
    for (int off = 1; off < 64; off <<= 1) {
        #pragma unroll
        for (int m = 0; m < NMIX; ++m) part[m] += __shfl_xor(part[m], off);
    }
    float mx = fmaxf(fmaxf(part[0], part[1]), fmaxf(part[2], part[3]));
    float e0 = __expf(part[0] - mx), e1 = __expf(part[1] - mx);
    float e2 = __expf(part[2] - mx), e3 = __expf(part[3] - mx);
    float z = e0 + e1 + e2 + e3;
    float mine = (l == 0) ? e0 : (l == 1) ? e1 : (l == 2) ? e2 : e3;
    if (l < NMIX) piOut[b * NMIX + l] = mine / z;
}

// ---------------------------------------------------------------------------
// Q A-fragment hoist from raw f32 query: A[row=q=lc][ch=lg*8+i]; qf[qt][m][c].
__device__ __forceinline__ void hoist_q2(const float* __restrict__ query,
                                         int b, int qrow0, int lg, int lc,
                                         bf16x8 qf[2][4][2]) {
    #pragma unroll
    for (int qt = 0; qt < 2; ++qt)
        #pragma unroll
        for (int m = 0; m < 4; ++m)
            #pragma unroll
            for (int c = 0; c < 2; ++c) {
                const float* src = query + ((size_t)b * DK + m * 64 + c * 32 + lg * 8) * LL
                                   + qrow0 + qt * 16 + lc;
                bf16x8 f;
                #pragma unroll
                for (int i = 0; i < 8; ++i) f[i] = (short)f2bf(src[(size_t)i * LL]);
                qf[qt][m][c] = f;
            }
}

// ---------------------------------------------------------------------------
// Z pre-pass (unchanged, known-good):
// Zh[kh][b][q][m] = sum_{k in half} exp2(S*ES)
__launch_bounds__(256, 4)
__global__ void zsum_k(const float* __restrict__ query,
                       const unsigned short* __restrict__ Kp,
                       float* __restrict__ Zh) {
    const int bid = blockIdx.x;
    const int b    = bid & 7;             // XCD affinity
    const int qt64 = (bid >> 3) & 63;
    const int kh   = bid >> 9;
    const int qb   = qt64 * 32;
    const int tid  = threadIdx.x;
    const int w = tid >> 6, lane = tid & 63, lg = lane >> 4, lc = lane & 15;

    bf16x8 qf[2][4][2];
    hoist_q2(query, b, qb, lg, lc, qf);

    const unsigned short* kpB = Kp + (size_t)b * 128 * 8 * 512;
    const float ES = 0.09016844005555896f;   // log2(e)/16

    float zs[2][4][4];
    #pragma unroll
    for (int qt = 0; qt < 2; ++qt)
        #pragma unroll
        for (int m = 0; m < 4; ++m)
            #pragma unroll
            for (int r = 0; r < 4; ++r) zs[qt][m][r] = 0.f;

    for (int t = 0; t < 16; ++t) {
        const int ktile = kh * 64 + w * 16 + t;
        const unsigned short* kp = kpB + (size_t)ktile * 8 * 512 + lane * 8;
        #pragma unroll
        for (int m = 0; m < 4; ++m) {
            bf16x8 k0 = *reinterpret_cast<const bf16x8*>(kp + (m * 2 + 0) * 512);
            bf16x8 k1 = *reinterpret_cast<const bf16x8*>(kp + (m * 2 + 1) * 512);
            #pragma unroll
            for (int qt = 0; qt < 2; ++qt) {
                f32x4 s = {0.f, 0.f, 0.f, 0.f};
                s = __builtin_amdgcn_mfma_f32_16x16x32_bf16(qf[qt][m][0], k0, s, 0, 0, 0);
                s = __builtin_amdgcn_mfma_f32_16x16x32_bf16(qf[qt][m][1], k1, s, 0, 0, 0);
                #pragma unroll
                for (int r = 0; r < 4; ++r)
                    zs[qt][m][r] += __builtin_amdgcn_exp2f(s[r] * ES);
            }
        }
    }
    #pragma unroll
    for (int qt = 0; qt < 2; ++qt)
        #pragma unroll
        for (int m = 0; m < 4; ++m)
            #pragma unroll
            for (int r = 0; r < 4; ++r) {
                float v = zs[qt][m][r];
                v += __shfl_xor(v, 1);
                v += __shfl_xor(v, 2);
                v += __shfl_xor(v, 4);
                v += __shfl_xor(v, 8);
                zs[qt][m][r] = v;
            }
    __shared__ float Zp[4][2][4][4][4];   // [w][qt][lg][m][r]
    if (lc == 0) {
        #pragma unroll
        for (int qt = 0; qt < 2; ++qt)
            #pragma unroll
            for (int m = 0; m < 4; ++m)
                #pragma unroll
                for (int r = 0; r < 4; ++r) Zp[w][qt][lg][m][r] = zs[qt][m][r];
    }
    __syncthreads();
    if (tid < 128) {
        const int q = tid >> 2, m = tid & 3;
        const int qt = q >> 4, g = (q >> 2) & 3, r = q & 3;
        float z = Zp[0][qt][g][m][r] + Zp[1][qt][g][m][r]
                + Zp[2][qt][g][m][r] + Zp[3][qt][g][m][r];
        Zh[(((size_t)kh * NB + b) * LL + qb + q) * NMIX + m] = z;
    }
}

// ---------------------------------------------------------------------------
// Main kernel v9: 512 threads / 8 waves, 2 blocks/CU (independent barrier
// groups), ONE barrier per 64-k window, K gl16-staged (dbuf), V double-
// buffered in REGISTERS, E XOR-swizzled (col ^= ((row>>2)&3)<<4).
// grid 512 = b(8, bid&7 -> XCD-local) x qt(64, 32 q-rows).
// Wave w: QK role (wq=w>>2, wk=w&3) -> 16q x 16k; PV role vj = {2w, 2w+1}.
__launch_bounds__(512, 4)
__global__ void mos_attn(const float* __restrict__ query,
                         const unsigned short* __restrict__ Kp,
                         const unsigned short* __restrict__ Vp,
                         const float* __restrict__ Zh,
                         const float* __restrict__ piAll,
                         float* __restrict__ out,
                         float* __restrict__ attn) {
    const int bid = blockIdx.x;
    const int b   = bid & 7;             // XCD affinity
    const int qt  = bid >> 3;            // 0..63
    const int qb  = qt * 32;
    const int tid = threadIdx.x;
    const int w = tid >> 6, lane = tid & 63, lg = lane >> 4, lc = lane & 15;
    const int wq = w >> 2, wk = w & 3;

    __shared__ __align__(16) unsigned short Ks[2][16384];   // 2 x 32KB (32 frags)
    __shared__ __align__(16) unsigned short E[2][32 * EP];  // 2 x 4.6KB

    // Q A-fragments for this wave's 16 q-rows: A[row=q=lc][ch]
    bf16x8 qf[4][2];
    #pragma unroll
    for (int m = 0; m < 4; ++m)
        #pragma unroll
        for (int c = 0; c < 2; ++c) {
            const float* src = query + ((size_t)b * DK + m * 64 + c * 32 + lg * 8) * LL
                               + qb + wq * 16 + lc;
            bf16x8 f;
            #pragma unroll
            for (int i = 0; i < 8; ++i) f[i] = (short)f2bf(src[(size_t)i * LL]);
            qf[m][c] = f;
        }

    // C[m][r] = log2(pi_m / Z) for q = qb + wq*16 + lg*4 + r
    float C[4][4];
    #pragma unroll
    for (int r = 0; r < 4; ++r) {
        const int q = qb + wq * 16 + lg * 4 + r;
        #pragma unroll
        for (int m = 0; m < 4; ++m) {
            float z = Zh[((size_t)b * LL + q) * NMIX + m]
                    + Zh[((size_t)(NB + b) * LL + q) * NMIX + m];
            C[m][r] = __log2f(piAll[b * NMIX + m] / z);
        }
    }

    const unsigned short* kpB = Kp + (size_t)b * 128 * 8 * 512;
    const unsigned short* vpB = Vp + (size_t)b * 64 * 16 * 512;
    const float ES = 0.09016844005555896f;    // log2(e)/16

    f32x4 oacc[2][2];   // [qg][vv]
    #pragma unroll
    for (int qg = 0; qg < 2; ++qg)
        #pragma unroll
        for (int vv = 0; vv < 2; ++vv) oacc[qg][vv] = (f32x4){0.f, 0.f, 0.f, 0.f};

    // attn streaming: row = tid>>4 (0..31), col = (tid&15)*4 (swizzled E read)
    const int erow = tid >> 4;
    const int ecolsw = ((tid & 15) * 4) ^ (((erow >> 2) & 3) << 4);
    float* arow = attn + ((size_t)b * LL + qb + erow) * LL + (tid & 15) * 4;

    bf16x8 vA[2][2], vB[2][2];   // named dbuf sets (rule #20: static indexing)

    // prologue: stage window 0 (K->LDS, V->vA)
    #pragma unroll
    for (int s = 0; s < 4; ++s)
        gl16(kpB + (size_t)(w * 4 + s) * 512 + lane * 8, &Ks[0][(w * 4 + s) * 512]);
    #pragma unroll
    for (int kc = 0; kc < 2; ++kc)
        #pragma unroll
        for (int vv = 0; vv < 2; ++vv)
            vA[kc][vv] = *reinterpret_cast<const bf16x8*>(
                vpB + ((size_t)(kc * 16) + 2 * w + vv) * 512 + lane * 8);
    __syncthreads();

    auto WIN = [&](int j, unsigned short* KCUR, unsigned short* KNXT,
                   unsigned short* ECUR, bf16x8 (&VCUR)[2][2], bf16x8 (&VNXT)[2][2]) {
        if (j < 31) {   // stage window j+1
            const size_t ksrc = (size_t)(j + 1) * 16384;
            #pragma unroll
            for (int s = 0; s < 4; ++s)
                gl16(kpB + ksrc + (w * 4 + s) * 512 + lane * 8, &KNXT[(w * 4 + s) * 512]);
            #pragma unroll
            for (int kc = 0; kc < 2; ++kc)
                #pragma unroll
                for (int vv = 0; vv < 2; ++vv)
                    VNXT[kc][vv] = *reinterpret_cast<const bf16x8*>(
                        vpB + ((size_t)((2 * (j + 1) + kc) * 16) + 2 * w + vv) * 512 + lane * 8);
        }
        // ---- QK: wave (wq,wk) -> 16q x 16k from LDS K frags ----
        {
            const unsigned short* kf = &KCUR[(wk * 8) * 512 + lane * 8];
            float av[4] = {0.f, 0.f, 0.f, 0.f};
            #pragma unroll
            for (int m = 0; m < 4; ++m) {
                bf16x8 k0 = *reinterpret_cast<const bf16x8*>(kf + (m * 2 + 0) * 512);
                bf16x8 k1 = *reinterpret_cast<const bf16x8*>(kf + (m * 2 + 1) * 512);
                f32x4 s = {0.f, 0.f, 0.f, 0.f};
                s = __builtin_amdgcn_mfma_f32_16x16x32_bf16(qf[m][0], k0, s, 0, 0, 0);
                s = __builtin_amdgcn_mfma_f32_16x16x32_bf16(qf[m][1], k1, s, 0, 0, 0);
                #pragma unroll
                for (int r = 0; r < 4; ++r)
                    av[r] += __builtin_amdgcn_exp2f(fmaf(s[r], ES, C[m][r]));
            }
            #pragma unroll
            for (int r = 0; r < 4; ++r)
                ECUR[(wq * 16 + lg * 4 + r) * EP + ((wk * 16 + lc) ^ (lg << 4))] =
                    f2bf(av[r]);
        }
        __syncthreads();   // single barrier: E ready; stage(j+1) drained

        // ---- PV: wave owns vj = {2w, 2w+1}; E as swizzled A-frags ----
        #pragma unroll
        for (int kc = 0; kc < 2; ++kc) {
            #pragma unroll
            for (int qg = 0; qg < 2; ++qg) {
                bf16x8 ea = *reinterpret_cast<const bf16x8*>(
                    &ECUR[(qg * 16 + lc) * EP + ((kc * 32 + lg * 8) ^ (((lc >> 2) & 3) << 4))]);
                #pragma unroll
                for (int vv = 0; vv < 2; ++vv)
                    oacc[qg][vv] = __builtin_amdgcn_mfma_f32_16x16x32_bf16(
                        ea, VCUR[kc][vv], oacc[qg][vv], 0, 0, 0);
            }
        }
        // ---- attn store: 32q x 64k tile, coalesced nontemporal f32x4 ----
        {
            bf16x4 e = *reinterpret_cast<const bf16x4*>(&ECUR[erow * EP + ecolsw]);
            f32x4 f;
            #pragma unroll
            for (int i = 0; i < 4; ++i) f[i] = bf2f((unsigned short)e[i]);
            nt_store4(arow + j * 64, f);
        }
        // no second barrier: next window writes the OTHER E/K buffers; this
        // wave's E/K reads complete before its next syncthreads (lgkmcnt 0).
    };

    for (int jj = 0; jj < 16; ++jj) {
        WIN(2 * jj + 0, Ks[0], Ks[1], E[0], vA, vB);
        WIN(2 * jj + 1, Ks[1], Ks[0], E[1], vB, vA);
    }

    // out: q = qb + qg*16 + lg*4 + r ; v = (2w+vv)*16 + lc
    #pragma unroll
    for (int qg = 0; qg < 2; ++qg)
        #pragma unroll
        for (int vv = 0; vv < 2; ++vv)
            #pragma unroll
            for (int r = 0; r < 4; ++r)
                out[((size_t)b * LL + qb + qg * 16 + lg * 4 + r) * DV
                    + (2 * w + vv) * 16 + lc] = oacc[qg][vv][r];
}

// ---------------------------------------------------------------------------
extern "C" void kernel_launch(void* const* d_in, const int* in_sizes, int n_in,
                              void* d_out, int out_size, void* d_ws, size_t ws_size,
                              hipStream_t stream) {
    const float* query   = (const float*)d_in[0];   // (8, 256, 2048)
    const float* key     = (const float*)d_in[1];   // (8, 256, 2048)
    const float* value   = (const float*)d_in[2];   // (8, 256, 2048)
    const float* weights = (const float*)d_in[3];   // (4, 256)

    float* out  = (float*)d_out;                    // (8, 2048, 256)
    float* attn = out + (size_t)NB * LL * DV;       // (8, 2048, 2048)

    // workspace (~17.3 MB)
    char* ws = (char*)d_ws;
    float* avg = (float*)ws;                              // 8KB
    float* pi  = (float*)(ws + 8192);                     // 32B
    float* Zh  = (float*)(ws + 12288);                    // 512KB
    unsigned short* Kp = (unsigned short*)(ws + 536576);  // 8.4MB packed K frags
    unsigned short* Vp = Kp + (size_t)NB * LL * DK;       // 8.4MB packed V frags

    avg_k<<<NB * DK, 256, 0, stream>>>(query, avg);
    pi_k<<<NB, 64, 0, stream>>>(weights, avg, pi);
    pack_kv<<<4096, 256, 0, stream>>>(key, value, Kp, Vp);
    zsum_k<<<1024, 256, 0, stream>>>(query, Kp, Zh);
    mos_attn<<<512, 512, 0, stream>>>(query, Kp, Vp, Zh, pi, out, attn);
}

// Round 10
// 122.544 us; speedup vs baseline: 1.2104x; 1.0125x over previous
//
#include <hip/hip_runtime.h>
#include <hip/hip_bf16.h>

// Problem constants (fixed by setup_inputs)
#define NB   8      // batch
#define DK   256    // dk (4 mixtures x 64)
#define LL   2048   // Lq == Lk
#define DV   256    // dv
#define NMIX 4
#define EP   72     // E pitch (shorts); rows 144B; swizzled cols

typedef __attribute__((ext_vector_type(8))) short bf16x8;
typedef __attribute__((ext_vector_type(4))) short bf16x4;
typedef __attribute__((ext_vector_type(4))) float f32x4;

__device__ __forceinline__ unsigned short f2bf(float x) {
    unsigned int u = __float_as_uint(x);
    return (unsigned short)((u + 0x7FFFu + ((u >> 16) & 1u)) >> 16);  // RNE
}
__device__ __forceinline__ float bf2f(unsigned short u) {
    return __uint_as_float(((unsigned int)u) << 16);
}
__device__ __forceinline__ void nt_store4(float* p, f32x4 v) {
    __builtin_nontemporal_store(v, reinterpret_cast<f32x4*>(p));
}
// async global->LDS: per-lane global src; LDS dest = uniform base + lane*16B
__device__ __forceinline__ void gl16(const unsigned short* g, unsigned short* l) {
    __builtin_amdgcn_global_load_lds(
        (const __attribute__((address_space(1))) unsigned int*)(const void*)g,
        (__attribute__((address_space(3))) unsigned int*)(void*)l, 16, 0, 0);
}

// ---------------------------------------------------------------------------
// Pack K and V into exact MFMA fragment order (contiguous 1KB per wave-frag).
// Kp[((b*128+kt16)*8+cc)*512 + lane*8+i] = bf16(K[b][cc*32+lg*8+i][kt16*16+lc])
// Vp[((b*64+kt32)*16+vj)*512 + lane*8+i] = bf16(V[b][vj*16+lc][kt32*32+lg*8+i])
__global__ void pack_kv(const float* __restrict__ key,
                        const float* __restrict__ value,
                        unsigned short* __restrict__ Kp,
                        unsigned short* __restrict__ Vp) {
    const int gid0 = blockIdx.x * 256 + threadIdx.x;
    if (blockIdx.x < 2048) {
        const int gid = gid0;                 // 0 .. 524287
        const int lane = gid & 63;
        const int cc   = (gid >> 6) & 7;      // 32-ch chunk
        const int kt   = (gid >> 9) & 127;    // 16-k tile
        const int b    = gid >> 16;
        const int lg = lane >> 4, lc = lane & 15;
        const float* src = key + ((size_t)b * DK + cc * 32 + lg * 8) * LL + kt * 16 + lc;
        bf16x8 o;
        #pragma unroll
        for (int i = 0; i < 8; ++i) o[i] = (short)f2bf(src[(size_t)i * LL]);
        *reinterpret_cast<bf16x8*>(Kp + (size_t)gid * 8) = o;
    } else {
        const int gid = gid0 - 2048 * 256;    // 0 .. 524287
        const int lane = gid & 63;
        const int vj   = (gid >> 6) & 15;
        const int kt   = (gid >> 10) & 63;    // 32-k tile
        const int b    = gid >> 16;
        const int lg = lane >> 4, lc = lane & 15;
        const float* src = value + ((size_t)b * DV + vj * 16 + lc) * LL + kt * 32 + lg * 8;
        float4 v0 = *reinterpret_cast<const float4*>(src);
        float4 v1 = *reinterpret_cast<const float4*>(src + 4);
        bf16x8 o;
        o[0] = (short)f2bf(v0.x); o[1] = (short)f2bf(v0.y);
        o[2] = (short)f2bf(v0.z); o[3] = (short)f2bf(v0.w);
        o[4] = (short)f2bf(v1.x); o[5] = (short)f2bf(v1.y);
        o[6] = (short)f2bf(v1.z); o[7] = (short)f2bf(v1.w);
        *reinterpret_cast<bf16x8*>(Vp + (size_t)gid * 8) = o;
    }
}

// avg_query: one block per (b*DK + d) row, mean over LL
__global__ void avg_k(const float* __restrict__ q, float* __restrict__ avg) {
    const int row = blockIdx.x;
    const float* p = q + (size_t)row * LL;
    float s = 0.f;
    for (int i = threadIdx.x; i < LL; i += 256) s += p[i];
    #pragma unroll
    for (int off = 32; off >= 1; off >>= 1) s += __shfl_down(s, off);
    __shared__ float ps[4];
    if ((threadIdx.x & 63) == 0) ps[threadIdx.x >> 6] = s;
    __syncthreads();
    if (threadIdx.x == 0)
        avg[row] = (ps[0] + ps[1] + ps[2] + ps[3]) * (1.0f / LL);
}

// pi = softmax_m( w[m,:] . avg[b,:] ) ; one wave per b
__global__ void pi_k(const float* __restrict__ wgt, const float* __restrict__ avg,
                     float* __restrict__ piOut) {
    const int b = blockIdx.x;
    const int l = threadIdx.x;   // 0..63
    float part[NMIX] = {0.f, 0.f, 0.f, 0.f};
    for (int d = l; d < DK; d += 64) {
        float a = avg[b * DK + d];
        #pragma unroll
        for (int m = 0; m < NMIX; ++m) part[m] += wgt[m * DK + d] * a;
    }
    #pragma unroll
    for (int off = 1; off < 64; off <<= 1) {
        #pragma unroll
        for (int m = 0; m < NMIX; ++m) part[m] += __shfl_xor(part[m], off);
    }
    float mx = fmaxf(fmaxf(part[0], part[1]), fmaxf(part[2], part[3]));
    float e0 = __expf(part[0] - mx), e1 = __expf(part[1] - mx);
    float e2 = __expf(part[2] - mx), e3 = __expf(part[3] - mx);
    float z = e0 + e1 + e2 + e3;
    float mine = (l == 0) ? e0 : (l == 1) ? e1 : (l == 2) ? e2 : e3;
    if (l < NMIX) piOut[b * NMIX + l] = mine / z;
}

// ---------------------------------------------------------------------------
// Q A-fragment hoist from raw f32 query: A[row=q=lc][ch=lg*8+i]; qf[qt][m][c].
__device__ __forceinline__ void hoist_q2(const float* __restrict__ query,
                                         int b, int qrow0, int lg, int lc,
                                         bf16x8 qf[2][4][2]) {
    #pragma unroll
    for (int qt = 0; qt < 2; ++qt)
        #pragma unroll
        for (int m = 0; m < 4; ++m)
            #pragma unroll
            for (int c = 0; c < 2; ++c) {
                const float* src = query + ((size_t)b * DK + m * 64 + c * 32 + lg * 8) * LL
                                   + qrow0 + qt * 16 + lc;
                bf16x8 f;
                #pragma unroll
                for (int i = 0; i < 8; ++i) f[i] = (short)f2bf(src[(size_t)i * LL]);
                qf[qt][m][c] = f;
            }
}

// ---------------------------------------------------------------------------
// Z pre-pass (unchanged, known-good):
// Zh[kh][b][q][m] = sum_{k in half} exp2(S*ES)
__launch_bounds__(256, 4)
__global__ void zsum_k(const float* __restrict__ query,
                       const unsigned short* __restrict__ Kp,
                       float* __restrict__ Zh) {
    const int bid = blockIdx.x;
    const int b    = bid & 7;             // XCD affinity
    const int qt64 = (bid >> 3) & 63;
    const int kh   = bid >> 9;
    const int qb   = qt64 * 32;
    const int tid  = threadIdx.x;
    const int w = tid >> 6, lane = tid & 63, lg = lane >> 4, lc = lane & 15;

    bf16x8 qf[2][4][2];
    hoist_q2(query, b, qb, lg, lc, qf);

    const unsigned short* kpB = Kp + (size_t)b * 128 * 8 * 512;
    const float ES = 0.09016844005555896f;   // log2(e)/16

    float zs[2][4][4];
    #pragma unroll
    for (int qt = 0; qt < 2; ++qt)
        #pragma unroll
        for (int m = 0; m < 4; ++m)
            #pragma unroll
            for (int r = 0; r < 4; ++r) zs[qt][m][r] = 0.f;

    for (int t = 0; t < 16; ++t) {
        const int ktile = kh * 64 + w * 16 + t;
        const unsigned short* kp = kpB + (size_t)ktile * 8 * 512 + lane * 8;
        #pragma unroll
        for (int m = 0; m < 4; ++m) {
            bf16x8 k0 = *reinterpret_cast<const bf16x8*>(kp + (m * 2 + 0) * 512);
            bf16x8 k1 = *reinterpret_cast<const bf16x8*>(kp + (m * 2 + 1) * 512);
            #pragma unroll
            for (int qt = 0; qt < 2; ++qt) {
                f32x4 s = {0.f, 0.f, 0.f, 0.f};
                s = __builtin_amdgcn_mfma_f32_16x16x32_bf16(qf[qt][m][0], k0, s, 0, 0, 0);
                s = __builtin_amdgcn_mfma_f32_16x16x32_bf16(qf[qt][m][1], k1, s, 0, 0, 0);
                #pragma unroll
                for (int r = 0; r < 4; ++r)
                    zs[qt][m][r] += __builtin_amdgcn_exp2f(s[r] * ES);
            }
        }
    }
    #pragma unroll
    for (int qt = 0; qt < 2; ++qt)
        #pragma unroll
        for (int m = 0; m < 4; ++m)
            #pragma unroll
            for (int r = 0; r < 4; ++r) {
                float v = zs[qt][m][r];
                v += __shfl_xor(v, 1);
                v += __shfl_xor(v, 2);
                v += __shfl_xor(v, 4);
                v += __shfl_xor(v, 8);
                zs[qt][m][r] = v;
            }
    __shared__ float Zp[4][2][4][4][4];   // [w][qt][lg][m][r]
    if (lc == 0) {
        #pragma unroll
        for (int qt = 0; qt < 2; ++qt)
            #pragma unroll
            for (int m = 0; m < 4; ++m)
                #pragma unroll
                for (int r = 0; r < 4; ++r) Zp[w][qt][lg][m][r] = zs[qt][m][r];
    }
    __syncthreads();
    if (tid < 128) {
        const int q = tid >> 2, m = tid & 3;
        const int qt = q >> 4, g = (q >> 2) & 3, r = q & 3;
        float z = Zp[0][qt][g][m][r] + Zp[1][qt][g][m][r]
                + Zp[2][qt][g][m][r] + Zp[3][qt][g][m][r];
        Zh[(((size_t)kh * NB + b) * LL + qb + q) * NMIX + m] = z;
    }
}

// ---------------------------------------------------------------------------
// Main kernel v10: R8 geometry (64q, read-once K+V -> 4.2 MB L2/CU) with
// R9 stall structure (ONE barrier/window, V in named reg dbuf, swizzled E).
// grid 256 = b(8, bid&7) x qt(32, 64 q-rows); 1024 thr / 16 waves.
// Wave w: QK role (wq=w>>2 -> 16q, wk=w&3 -> 16k); PV role vj = w.
// Per 64-k window: {stage K(j+1) via gl16 + V(j+1)->regs; QK -> E[cur];
//  barrier; attn store (early, stream writes); PV from E[cur] + Vregs}.
__launch_bounds__(1024, 4)
__global__ void mos_attn(const float* __restrict__ query,
                         const unsigned short* __restrict__ Kp,
                         const unsigned short* __restrict__ Vp,
                         const float* __restrict__ Zh,
                         const float* __restrict__ piAll,
                         float* __restrict__ out,
                         float* __restrict__ attn) {
    const int bid = blockIdx.x;
    const int b   = bid & 7;             // XCD affinity
    const int qt  = bid >> 3;            // 0..31
    const int qb  = qt * 64;
    const int tid = threadIdx.x;
    const int w = tid >> 6, lane = tid & 63, lg = lane >> 4, lc = lane & 15;
    const int wq = w >> 2, wk = w & 3;

    __shared__ __align__(16) unsigned short Ks[2][16384];   // 2 x 32KB (32 frags)
    __shared__ __align__(16) unsigned short E[2][64 * EP];  // 2 x 9.2KB

    // Q A-fragments for this wave's 16 q-rows: A[row=q=lc][ch]
    bf16x8 qf[4][2];
    #pragma unroll
    for (int m = 0; m < 4; ++m)
        #pragma unroll
        for (int c = 0; c < 2; ++c) {
            const float* src = query + ((size_t)b * DK + m * 64 + c * 32 + lg * 8) * LL
                               + qb + wq * 16 + lc;
            bf16x8 f;
            #pragma unroll
            for (int i = 0; i < 8; ++i) f[i] = (short)f2bf(src[(size_t)i * LL]);
            qf[m][c] = f;
        }

    // C[m][r] = log2(pi_m / Z) for q = qb + wq*16 + lg*4 + r
    float C[4][4];
    #pragma unroll
    for (int r = 0; r < 4; ++r) {
        const int q = qb + wq * 16 + lg * 4 + r;
        #pragma unroll
        for (int m = 0; m < 4; ++m) {
            float z = Zh[((size_t)b * LL + q) * NMIX + m]
                    + Zh[((size_t)(NB + b) * LL + q) * NMIX + m];
            C[m][r] = __log2f(piAll[b * NMIX + m] / z);
        }
    }

    const unsigned short* kpB = Kp + (size_t)b * 128 * 8 * 512;
    const unsigned short* vpB = Vp + (size_t)b * 64 * 16 * 512;
    const float ES = 0.09016844005555896f;    // log2(e)/16

    f32x4 oacc[4];
    #pragma unroll
    for (int qg = 0; qg < 4; ++qg) oacc[qg] = (f32x4){0.f, 0.f, 0.f, 0.f};

    // attn streaming: row = tid>>4 (0..63), col = (tid&15)*4 (swizzled E read)
    const int erow = tid >> 4;
    const int ecolsw = ((tid & 15) * 4) ^ (((erow >> 2) & 3) << 4);
    float* arow = attn + ((size_t)b * LL + qb + erow) * LL + (tid & 15) * 4;

    bf16x8 vA[2], vB[2];   // named dbuf V sets (rule #20: static indexing)

    // prologue: stage window 0 (K->Ks[0] via gl16; V->vA)
    gl16(kpB + (size_t)(w * 2 + 0) * 512 + lane * 8, &Ks[0][(w * 2 + 0) * 512]);
    gl16(kpB + (size_t)(w * 2 + 1) * 512 + lane * 8, &Ks[0][(w * 2 + 1) * 512]);
    #pragma unroll
    for (int kc = 0; kc < 2; ++kc)
        vA[kc] = *reinterpret_cast<const bf16x8*>(
            vpB + ((size_t)kc * 16 + w) * 512 + lane * 8);
    __syncthreads();

    auto WIN = [&](int j, unsigned short* KCUR, unsigned short* KNXT,
                   unsigned short* ECUR, bf16x8 (&VCUR)[2], bf16x8 (&VNXT)[2]) {
        if (j < 31) {   // stage window j+1 (K -> LDS other buf, V -> other regs)
            const size_t ksrc = (size_t)(j + 1) * 16384;
            gl16(kpB + ksrc + (w * 2 + 0) * 512 + lane * 8, &KNXT[(w * 2 + 0) * 512]);
            gl16(kpB + ksrc + (w * 2 + 1) * 512 + lane * 8, &KNXT[(w * 2 + 1) * 512]);
            #pragma unroll
            for (int kc = 0; kc < 2; ++kc)
                VNXT[kc] = *reinterpret_cast<const bf16x8*>(
                    vpB + ((size_t)(2 * (j + 1) + kc) * 16 + w) * 512 + lane * 8);
        }
        // ---- QK: wave (wq,wk) -> 16q x 16k from LDS K frags ----
        {
            const unsigned short* kf = &KCUR[(wk * 8) * 512 + lane * 8];
            float av[4] = {0.f, 0.f, 0.f, 0.f};
            #pragma unroll
            for (int m = 0; m < 4; ++m) {
                bf16x8 k0 = *reinterpret_cast<const bf16x8*>(kf + (m * 2 + 0) * 512);
                bf16x8 k1 = *reinterpret_cast<const bf16x8*>(kf + (m * 2 + 1) * 512);
                f32x4 s = {0.f, 0.f, 0.f, 0.f};
                s = __builtin_amdgcn_mfma_f32_16x16x32_bf16(qf[m][0], k0, s, 0, 0, 0);
                s = __builtin_amdgcn_mfma_f32_16x16x32_bf16(qf[m][1], k1, s, 0, 0, 0);
                #pragma unroll
                for (int r = 0; r < 4; ++r)
                    av[r] += __builtin_amdgcn_exp2f(fmaf(s[r], ES, C[m][r]));
            }
            // row = wq*16 + lg*4 + r (0..63); col = (wk*16+lc) ^ row-XOR
            #pragma unroll
            for (int r = 0; r < 4; ++r)
                ECUR[(wq * 16 + lg * 4 + r) * EP + ((wk * 16 + lc) ^ (lg << 4))] =
                    f2bf(av[r]);
        }
        __syncthreads();   // single barrier: E ready; stage(j+1) drained

        // ---- attn store first: get the write stream flowing ----
        {
            bf16x4 e = *reinterpret_cast<const bf16x4*>(&ECUR[erow * EP + ecolsw]);
            f32x4 f;
            #pragma unroll
            for (int i = 0; i < 4; ++i) f[i] = bf2f((unsigned short)e[i]);
            nt_store4(arow + j * 64, f);
        }

        // ---- PV: wave owns vj = w; k = 64 window (2 chunks of 32) ----
        #pragma unroll
        for (int kc = 0; kc < 2; ++kc) {
            #pragma unroll
            for (int qg = 0; qg < 4; ++qg) {
                bf16x8 ea = *reinterpret_cast<const bf16x8*>(
                    &ECUR[(qg * 16 + lc) * EP
                          + ((kc * 32 + lg * 8) ^ (((lc >> 2) & 3) << 4))]);
                oacc[qg] = __builtin_amdgcn_mfma_f32_16x16x32_bf16(
                    ea, VCUR[kc], oacc[qg], 0, 0, 0);
            }
        }
        // no second barrier: next window uses the OTHER E/K buffers; a wave
        // reaching window j+2's QK has passed BAR(j+1), which implies every
        // wave finished PV(j) -> E/K buffer reuse is race-free.
    };

    for (int jj = 0; jj < 16; ++jj) {
        WIN(2 * jj + 0, Ks[0], Ks[1], E[0], vA, vB);
        WIN(2 * jj + 1, Ks[1], Ks[0], E[1], vB, vA);
    }

    // out: q = qb + qg*16 + lg*4 + r ; v = w*16 + lc
    #pragma unroll
    for (int qg = 0; qg < 4; ++qg)
        #pragma unroll
        for (int r = 0; r < 4; ++r)
            out[((size_t)b * LL + qb + qg * 16 + lg * 4 + r) * DV + w * 16 + lc] =
                oacc[qg][r];
}

// ---------------------------------------------------------------------------
extern "C" void kernel_launch(void* const* d_in, const int* in_sizes, int n_in,
                              void* d_out, int out_size, void* d_ws, size_t ws_size,
                              hipStream_t stream) {
    const float* query   = (const float*)d_in[0];   // (8, 256, 2048)
    const float* key     = (const float*)d_in[1];   // (8, 256, 2048)
    const float* value   = (const float*)d_in[2];   // (8, 256, 2048)
    const float* weights = (const float*)d_in[3];   // (4, 256)

    float* out  = (float*)d_out;                    // (8, 2048, 256)
    float* attn = out + (size_t)NB * LL * DV;       // (8, 2048, 2048)

    // workspace (~17.3 MB)
    char* ws = (char*)d_ws;
    float* avg = (float*)ws;                              // 8KB
    float* pi  = (float*)(ws + 8192);                     // 32B
    float* Zh  = (float*)(ws + 12288);                    // 512KB
    unsigned short* Kp = (unsigned short*)(ws + 536576);  // 8.4MB packed K frags
    unsigned short* Vp = Kp + (size_t)NB * LL * DK;       // 8.4MB packed V frags

    avg_k<<<NB * DK, 256, 0, stream>>>(query, avg);
    pi_k<<<NB, 64, 0, stream>>>(weights, avg, pi);
    pack_kv<<<4096, 256, 0, stream>>>(key, value, Kp, Vp);
    zsum_k<<<1024, 256, 0, stream>>>(query, Kp, Zh);
    mos_attn<<<256, 1024, 0, stream>>>(query, Kp, Vp, Zh, pi, out, attn);
}